// Round 4
// baseline (34.921 us; speedup 1.0000x reference)
//
#include <hip/hip_runtime.h>

#define B_SZ 32
#define T_PH 512
#define H_DIM 256
#define N_EDGES 255
#define MAX_LEN 4096
#define FPB 16   // frames per expand block

typedef float f32x4 __attribute__((ext_vector_type(4)));

// ---------------- Kernel A: shfl-scan + bin bisects + packed-frame fill ----------
// One block (512 thr) per batch row. frames[b][t] = ph | pi<<9 | ei<<17 (or -1)
__global__ void prep_kernel(const int* __restrict__ dur,
                            const float* __restrict__ pt,
                            const float* __restrict__ et,
                            const float* __restrict__ pbins,
                            const float* __restrict__ ebins,
                            int* __restrict__ frames,
                            float* __restrict__ mel_out) {
    const int b = blockIdx.x;
    const int tid = threadIdx.x;
    const int wave = tid >> 6;
    const int lane = tid & 63;
    __shared__ int cs[T_PH];
    __shared__ int packv[T_PH];
    __shared__ int wsum[8];
    __shared__ float pb[N_EDGES];
    __shared__ float eb[N_EDGES];

    if (tid < N_EDGES) pb[tid] = pbins[tid];
    else if (tid >= 256 && tid < 256 + N_EDGES) eb[tid - 256] = ebins[tid - 256];

    const int d = dur[b * T_PH + tid];
    // wave-level inclusive scan (no barriers)
    int v = d;
#pragma unroll
    for (int off = 1; off < 64; off <<= 1) {
        int u = __shfl_up(v, off, 64);
        if (lane >= off) v += u;
    }
    if (lane == 63) wsum[wave] = v;
    __syncthreads();
    int woff = 0;
#pragma unroll
    for (int w = 0; w < 8; ++w) woff += (w < wave) ? wsum[w] : 0;
    v += woff;
    cs[tid] = v;

    // per-phoneme bin bisects (side='left'), bins in LDS
    const float pv = pt[b * T_PH + tid];
    const float ev = et[b * T_PH + tid];
    int lo = 0, hi = N_EDGES;
    while (lo < hi) { int m = (lo + hi) >> 1; if (pb[m] < pv) lo = m + 1; else hi = m; }
    const int pi = lo;
    lo = 0; hi = N_EDGES;
    while (lo < hi) { int m = (lo + hi) >> 1; if (eb[m] < ev) lo = m + 1; else hi = m; }
    const int ei = lo;
    packv[tid] = tid | (pi << 9) | (ei << 17);
    __syncthreads();

    const int mel = cs[T_PH - 1];

    // each thread resolves 8 consecutive frames: one LDS bisect + monotone walk
    const int t0 = tid * 8;
    int p = 0;
    if (t0 < mel) {
        int l = 0, h = T_PH;   // searchsorted(cs, t0, side='right')
        while (l < h) { int m = (l + h) >> 1; if (cs[m] > t0) h = m; else l = m + 1; }
        p = l;
    }
    int o[8];
#pragma unroll
    for (int j = 0; j < 8; ++j) {
        const int t = t0 + j;
        int vv = -1;
        if (t < mel) {
            while (cs[p] <= t) ++p;
            vv = packv[p];
        }
        o[j] = vv;
    }
    int4* fr = (int4*)(frames + (size_t)b * MAX_LEN);
    fr[tid * 2]     = make_int4(o[0], o[1], o[2], o[3]);
    fr[tid * 2 + 1] = make_int4(o[4], o[5], o[6], o[7]);

    if (tid == T_PH - 1) mel_out[b] = (float)mel;  // exact for < 2^24
}

// ---------------- Kernel B: 16 frames/block, 4 per wave, staged for ILP ----------
__global__ void expand_kernel(const float* __restrict__ x,
                              const float* __restrict__ pemb,
                              const float* __restrict__ eemb,
                              const int* __restrict__ frames,
                              float* __restrict__ out) {
    const int wave  = threadIdx.x >> 6;          // 0..3
    const int lane4 = threadIdx.x & 63;
    const int base  = blockIdx.x * FPB;

    int pk[4];
#pragma unroll
    for (int j = 0; j < 4; ++j)
        pk[j] = frames[base + j * 4 + wave];     // uniform per wave

    f32x4 val[4];
#pragma unroll
    for (int j = 0; j < 4; ++j) {
        const int k = pk[j];
        f32x4 r = {0.f, 0.f, 0.f, 0.f};
        if (k >= 0) {
            const int frame = base + j * 4 + wave;
            const int b  = frame >> 12;
            const int ph = k & 511;
            const int pi = (k >> 9) & 255;
            const int ei = (k >> 17) & 255;
            const f32x4 a = ((const f32x4*)(x    + (size_t)(b * T_PH + ph) * H_DIM))[lane4];
            const f32x4 p = ((const f32x4*)(pemb + (size_t)pi * H_DIM))[lane4];
            const f32x4 e = ((const f32x4*)(eemb + (size_t)ei * H_DIM))[lane4];
            r = a + p + e;
        }
        val[j] = r;
    }
#pragma unroll
    for (int j = 0; j < 4; ++j) {
        const int frame = base + j * 4 + wave;
        __builtin_nontemporal_store(val[j], (f32x4*)out + (size_t)frame * 64 + lane4);
    }
}

extern "C" void kernel_launch(void* const* d_in, const int* in_sizes, int n_in,
                              void* d_out, int out_size, void* d_ws, size_t ws_size,
                              hipStream_t stream) {
    const float* x     = (const float*)d_in[0];
    const float* pt    = (const float*)d_in[1];
    const float* et    = (const float*)d_in[2];
    const float* pbins = (const float*)d_in[3];
    const float* ebins = (const float*)d_in[4];
    const float* pemb  = (const float*)d_in[5];
    const float* eemb  = (const float*)d_in[6];
    const int*   dur   = (const int*)d_in[7];

    float* out = (float*)d_out;                            // 32*4096*256 f32
    float* mel_out = out + (size_t)B_SZ * MAX_LEN * H_DIM; // 32 f32 (tuple tail)

    int* frames = (int*)d_ws;                              // 512 KB packed indices

    prep_kernel<<<B_SZ, T_PH, 0, stream>>>(dur, pt, et, pbins, ebins,
                                           frames, mel_out);

    const int nframes = B_SZ * MAX_LEN;                    // 131072
    expand_kernel<<<nframes / FPB, 256, 0, stream>>>(x, pemb, eemb, frames, out);
}